// Round 8
// baseline (950.033 us; speedup 1.0000x reference)
//
#include <hip/hip_runtime.h>
#include <utility>

// Problem constants: DIM_IN=128, DIM_OUT=128, DIM_X=256, L=256, BATCH=8192, fp32.
#define NB 8192

// ---------- static_for helper (compile-time register indices) ----------
template <typename F, size_t... I>
__device__ __forceinline__ void sfor_impl(F&& f, std::index_sequence<I...>) {
  (f(std::integral_constant<int, (int)I>{}), ...);
}
template <int N, typename F>
__device__ __forceinline__ void sfor(F&& f) {
  sfor_impl((F&&)f, std::make_index_sequence<N>{});
}

// packed-column-triangle offset: column li holds D[l2][li], l2=li+1..63, padded to x4
constexpr int coff(int li) {
  int o = 0;
  for (int j = 0; j < li; ++j) o += ((63 - j) + 3) & ~3;
  return o;
}
#define CPACK_STRIDE 2176  // > coff(63), float4-aligned

// fast tanh: 1 - 2/(exp(2x)+1). Correct limits at +/-inf.
__device__ __forceinline__ float fast_tanh(float x) {
  const float e = __expf(2.0f * x);
  return 1.0f - 2.0f / (e + 1.0f);
}

// ---------- hand-rolled grid barrier (normal launch; all 256 blocks co-resident) --
// Per-phase monotone counters (zeroed by hipMemsetAsync before the kernel, which is
// part of the captured graph). Agent-scope acq_rel atomics handle cross-XCD L2
// visibility (G16); no reset needed within a launch.
__device__ __forceinline__ void gbar(unsigned* cnt, int nb) {
  __syncthreads();
  if (threadIdx.x == 0) {
    __hip_atomic_fetch_add(cnt, 1u, __ATOMIC_ACQ_REL, __HIP_MEMORY_SCOPE_AGENT);
    while (__hip_atomic_load(cnt, __ATOMIC_ACQUIRE, __HIP_MEMORY_SCOPE_AGENT) <
           (unsigned)nb) {
    }
  }
  __syncthreads();
}

// =================== device phase functions (verified bodies) ===================

__device__ void dev_prep(const float* __restrict__ x, const float* __restrict__ C1,
                         const float* __restrict__ Fm, const float* __restrict__ Lam,
                         float* __restrict__ cx, float* __restrict__ xF,
                         float* __restrict__ rLam, int t) {
  float s1 = 0.f, s2 = 0.f;
  for (int i = 0; i < 256; ++i) {
    const float xi = x[i];
    s1 += C1[t * 256 + i] * xi;
    s2 += Fm[t * 256 + i] * xi;
  }
  cx[t] = s1;
  xF[t] = s2;
  rLam[t] = 1.0f / Lam[t];
}

__device__ void dev_pack(const float* __restrict__ D11, float* __restrict__ cpack,
                         int t) {
  const int c = t >> 6;
  const int lane = t & 63;
  int off = 0;
  for (int li = 0; li < 63; ++li) {
    if (lane < 63 - li)
      cpack[c * CPACK_STRIDE + off + lane] =
          D11[(c * 64 + li + 1 + lane) * 256 + (c * 64 + li)];
    off += ((63 - li) + 3) & ~3;
  }
}

// blocked-panel GJ inverse of 128x128, streaming phase-2 (no spills)
__device__ void dev_inv(const float* __restrict__ srcT, int ld,
                        float* __restrict__ dstT, int tid, float* sm) {
  float* Pc = sm;               // [16][132] panel cols (col-major)
  float* MBt = sm + 16 * 132;   // [16][132] M transposed
  float* Ar = sm + 32 * 132;    // [16][132] old panel rows
  float* invD = sm + 48 * 132;  // [16][20]
  const int ti = tid >> 4, tj = tid & 15;
  const int R = ti * 8, C = tj * 8;
  float a[8][8];
#pragma unroll
  for (int i = 0; i < 8; ++i)
#pragma unroll
    for (int j = 0; j < 8; ++j) a[i][j] = srcT[(C + j) * ld + (R + i)];

  for (int s = 0; s < 8; ++s) {
    if ((tj >> 1) == s) {
      const int c0 = (tj & 1) * 8;
#pragma unroll
      for (int j = 0; j < 8; ++j)
#pragma unroll
        for (int i = 0; i < 8; ++i) Pc[(c0 + j) * 132 + R + i] = a[i][j];
    }
    if ((ti >> 1) == s) {
      const int r0 = (ti & 1) * 8;
#pragma unroll
      for (int i = 0; i < 8; ++i)
#pragma unroll
        for (int j = 0; j < 8; ++j) Ar[(r0 + i) * 132 + C + j] = a[i][j];
    }
    __syncthreads();

    if (tid < 16) {
      float q[16];
#pragma unroll
      for (int j = 0; j < 16; ++j) q[j] = Pc[j * 132 + s * 16 + tid];
#pragma unroll
      for (int kk = 0; kk < 16; ++kk) {
        float ps[16];
#pragma unroll
        for (int j = 0; j < 16; ++j) ps[j] = __shfl(q[j], kk, 16);
        const float piv = 1.0f / ps[kk];
#pragma unroll
        for (int j = 0; j < 16; ++j) ps[j] = (j == kk) ? piv : ps[j] * piv;
        const bool isP = (tid == kk);
        const float te = isP ? -1.0f : q[kk];
#pragma unroll
        for (int j = 0; j < 16; ++j) {
          const float base = (isP || j == kk) ? 0.0f : q[j];
          q[j] = base - te * ps[j];
        }
      }
#pragma unroll
      for (int j = 0; j < 16; ++j) invD[tid * 20 + j] = q[j];
    }
    __syncthreads();

    {
      const int r = tid & 127, h = tid >> 7;
      float mv[8];
      if ((r >> 4) == s) {
        const int rr = r & 15;
#pragma unroll
        for (int j = 0; j < 8; ++j) mv[j] = invD[rr * 20 + 8 * h + j];
      } else {
#pragma unroll
        for (int j = 0; j < 8; ++j) mv[j] = 0.f;
#pragma unroll
        for (int k = 0; k < 16; ++k) {
          const float pk = Pc[k * 132 + r];
          const float4 d0 = *(const float4*)&invD[k * 20 + 8 * h];
          const float4 d1 = *(const float4*)&invD[k * 20 + 8 * h + 4];
          mv[0] -= pk * d0.x; mv[1] -= pk * d0.y; mv[2] -= pk * d0.z; mv[3] -= pk * d0.w;
          mv[4] -= pk * d1.x; mv[5] -= pk * d1.y; mv[6] -= pk * d1.z; mv[7] -= pk * d1.w;
        }
      }
#pragma unroll
      for (int j = 0; j < 8; ++j) MBt[(8 * h + j) * 132 + r] = mv[j];
    }
    __syncthreads();

    if ((tj >> 1) == s) {
      const int c0 = (tj & 1) * 8;
#pragma unroll
      for (int j = 0; j < 8; ++j)
#pragma unroll
        for (int i = 0; i < 8; ++i) a[i][j] = MBt[(c0 + j) * 132 + R + i];
    } else {
      if ((ti >> 1) == s) {
#pragma unroll
        for (int i = 0; i < 8; ++i)
#pragma unroll
          for (int j = 0; j < 8; ++j) a[i][j] = 0.f;
      }
#pragma unroll
      for (int kk = 0; kk < 16; ++kk) {
        const float4 m0 = *(const float4*)&MBt[kk * 132 + R];
        const float4 m1 = *(const float4*)&MBt[kk * 132 + R + 4];
        const float4 p0 = *(const float4*)&Ar[kk * 132 + C];
        const float4 p1 = *(const float4*)&Ar[kk * 132 + C + 4];
        const float mi[8] = {m0.x, m0.y, m0.z, m0.w, m1.x, m1.y, m1.z, m1.w};
        const float pj[8] = {p0.x, p0.y, p0.z, p0.w, p1.x, p1.y, p1.z, p1.w};
#pragma unroll
        for (int i = 0; i < 8; ++i)
#pragma unroll
          for (int j = 0; j < 8; ++j) a[i][j] += mi[i] * pj[j];
      }
    }
    __syncthreads();
  }
#pragma unroll
  for (int i = 0; i < 8; ++i)
#pragma unroll
    for (int j = 0; j < 8; ++j) dstT[(C + j) * 128 + (R + i)] = a[i][j];
}

__device__ void dev_T(const float* __restrict__ u, float* __restrict__ vw, int bid,
                      int t, float* sm) {
  float* buf = sm;  // 64*65
  const int b0 = bid * 64;
#pragma unroll
  for (int h = 0; h < 2; ++h) {
#pragma unroll
    for (int q = 0; q < 16; ++q) {
      const int idx = q * 256 + t;
      const int bl = idx >> 6;
      const int i2 = idx & 63;
      buf[i2 * 65 + bl] = u[(b0 + bl) * 128 + 64 * h + i2];
    }
    __syncthreads();
#pragma unroll
    for (int q = 0; q < 16; ++q) {
      const int idx = q * 256 + t;
      const int i2 = idx >> 6;
      const int bl = idx & 63;
      vw[(256 + 64 * h + i2) * NB + b0 + bl] = buf[i2 * 65 + bl];
    }
    __syncthreads();
  }
}

__device__ void dev_du(const float* __restrict__ D12, const float* __restrict__ cx,
                       float* __restrict__ vw, int bid, int t, float* sm) {
  float* Dl = sm;  // 8*128
  const int bx = bid & 7;
  const int l0 = (bid >> 3) * 8;
#pragma unroll
  for (int q = 0; q < 4; ++q) Dl[q * 256 + t] = D12[l0 * 128 + q * 256 + t];
  __syncthreads();
  const float4* vw4 = (const float4*)vw;
  float4* vw4o = (float4*)vw;
  const int b4 = bx * 256 + t;
  float4 acc[8];
#pragma unroll
  for (int j = 0; j < 8; ++j) {
    const float cj = cx[l0 + j];
    acc[j] = make_float4(cj, cj, cj, cj);
  }
#pragma unroll 4
  for (int i = 0; i < 128; ++i) {
    const float4 wv = vw4[(256 + i) * 2048 + b4];
#pragma unroll
    for (int j = 0; j < 8; ++j) {
      const float d = Dl[j * 128 + i];
      acc[j].x += d * wv.x;
      acc[j].y += d * wv.y;
      acc[j].z += d * wv.z;
      acc[j].w += d * wv.w;
    }
  }
#pragma unroll
  for (int j = 0; j < 8; ++j) vw4o[(l0 + j) * 2048 + b4] = acc[j];
  __syncthreads();
}

__device__ void dev_WZ(const float* __restrict__ E, const float* __restrict__ C2,
                       const float* __restrict__ inv1T, float* __restrict__ W,
                       float* __restrict__ z1, int gid) {
  const int half = gid >> 14;
  const int idx = gid & 16383;
  const int j = idx >> 7;
  const int i = idx & 127;
  float s = 0.f;
  if (half == 0) {
    for (int m = 0; m < 128; ++m) s += inv1T[m * 128 + i] * E[(128 + j) * 256 + m];
    W[i * 128 + j] = s;
  } else {
    for (int m = 0; m < 128; ++m) s += inv1T[m * 128 + i] * C2[j * 256 + m];
    z1[i * 128 + j] = s;
  }
}

__device__ void dev_SC(const float* __restrict__ E, const float* __restrict__ C2,
                       const float* __restrict__ W, const float* __restrict__ z1,
                       float* __restrict__ STt, float* __restrict__ c2p, int gid) {
  if (gid < 16384) {
    const int jj = gid >> 7;
    const int i = gid & 127;
    float s = E[(128 + jj) * 256 + 128 + i];
    for (int m = 0; m < 128; ++m) s -= E[m * 256 + 128 + i] * W[m * 128 + jj];
    STt[jj * 128 + i] = s;
  } else {
    const int idx = gid - 16384;
    const int i = idx >> 7;
    const int o = idx & 127;
    float s = C2[o * 256 + 128 + i];
    for (int m = 0; m < 128; ++m) s -= E[m * 256 + 128 + i] * z1[m * 128 + o];
    c2p[i * 128 + o] = s;
  }
}

__device__ void dev_G2(const float* __restrict__ inv2T, const float* __restrict__ c2p,
                       float* __restrict__ g2, int gid) {
  const int i = gid >> 7;
  const int o = gid & 127;
  float s = 0.f;
  for (int m = 0; m < 128; ++m) s += inv2T[m * 128 + i] * c2p[m * 128 + o];
  g2[i * 128 + o] = s;
}

__device__ void dev_G1(const float* __restrict__ W, const float* __restrict__ z1,
                       const float* __restrict__ g2, float* __restrict__ g1, int gid) {
  const int i = gid >> 7;
  const int o = gid & 127;
  float s = z1[i * 128 + o];
  for (int m = 0; m < 128; ++m) s -= W[i * 128 + m] * g2[m * 128 + o];
  g1[i * 128 + o] = s;
}

__device__ void dev_R(const float* __restrict__ B1, const float* __restrict__ B2,
                      const float* __restrict__ D21, const float* __restrict__ D22,
                      const float* __restrict__ g1, const float* __restrict__ g2,
                      const float* __restrict__ xF, float* __restrict__ R,
                      float* __restrict__ y0, int gid) {
  if (gid < 32768) {
    const int o = gid >> 8;
    const int l = gid & 255;
    float s = D21[o * 256 + l];
    for (int m = 0; m < 128; ++m) {
      s += g1[m * 128 + o] * B1[m * 256 + l];
      s += g2[m * 128 + o] * B1[(128 + m) * 256 + l];
    }
    R[o * 384 + l] = s;
  } else if (gid < 49152) {
    const int t2 = gid - 32768;
    const int o = t2 >> 7;
    const int i = t2 & 127;
    float s = D22[o * 128 + i];
    for (int m = 0; m < 128; ++m) {
      s += g1[m * 128 + o] * B2[m * 128 + i];
      s += g2[m * 128 + o] * B2[(128 + m) * 128 + i];
    }
    R[o * 384 + 256 + i] = s;
  } else if (gid < 49280) {
    const int o = gid - 49152;
    float s = 0.f;
    for (int m = 0; m < 128; ++m) {
      s += g1[m * 128 + o] * xF[m];
      s += g2[m * 128 + o] * xF[128 + m];
    }
    y0[o] = s;
  }
}

__device__ void dev_scan(const float* __restrict__ cpack,
                         const float* __restrict__ rLam, float* __restrict__ vw,
                         int c, int bid, int t) {
  const int b = bid * 256 + t;
  const int l0 = c * 64;
  const float4* cp4 = (const float4*)(cpack + c * CPACK_STRIDE);
  float v[64];
#pragma unroll
  for (int li = 0; li < 64; ++li) v[li] = vw[(l0 + li) * NB + b];
  sfor<64>([&](auto LI) {
    constexpr int li = decltype(LI)::value;
    const float w = fast_tanh(v[li] * rLam[l0 + li]);
    vw[(l0 + li) * NB + b] = w;
    constexpr int n = 63 - li;
    constexpr int off4 = coff(li) / 4;
    sfor<(n + 3) / 4>([&](auto Q) {
      constexpr int q = decltype(Q)::value;
      const float4 d = cp4[off4 + q];
      if constexpr (4 * q + 0 < n) v[li + 1 + 4 * q + 0] += d.x * w;
      if constexpr (4 * q + 1 < n) v[li + 1 + 4 * q + 1] += d.y * w;
      if constexpr (4 * q + 2 < n) v[li + 1 + 4 * q + 2] += d.z * w;
      if constexpr (4 * q + 3 < n) v[li + 1 + 4 * q + 3] += d.w * w;
    });
  });
}

__device__ void dev_upd(const float* __restrict__ D11, float* __restrict__ vw, int c,
                        int bid, int t) {
  float4* vw4 = (float4*)vw;
  const int b4 = (bid & 7) * 256 + t;
  const int lp0 = (c + 1) * 64 + (bid >> 3) * 8;
  const int k0 = c * 64;
  float4 acc[8];
#pragma unroll
  for (int j = 0; j < 8; ++j) acc[j] = vw4[(lp0 + j) * 2048 + b4];
  for (int k = 0; k < 64; ++k) {
    const float4 wv = vw4[(k0 + k) * 2048 + b4];
#pragma unroll
    for (int j = 0; j < 8; ++j) {
      const float d = D11[(lp0 + j) * 256 + k0 + k];  // wave-uniform scalar
      acc[j].x += d * wv.x;
      acc[j].y += d * wv.y;
      acc[j].z += d * wv.z;
      acc[j].w += d * wv.w;
    }
  }
#pragma unroll
  for (int j = 0; j < 8; ++j) vw4[(lp0 + j) * 2048 + b4] = acc[j];
}

__device__ void dev_ky(const float* __restrict__ vw, const float* __restrict__ R,
                       const float* __restrict__ y0, float* __restrict__ y, int bid,
                       int tid, float* sm) {
  float* Rl = sm;  // 1536
  const int gx = bid & 7;   // b-tile (XCD-aligned)
  const int gy = bid >> 3;  // o-tile
  const int o0 = gy * 4;
#pragma unroll
  for (int q = 0; q < 6; ++q) Rl[q * 256 + tid] = R[o0 * 384 + q * 256 + tid];
  __syncthreads();
  const float4* vw4 = (const float4*)vw;
  const int b4 = gx * 256 + tid;
  float acc[4][4];
#pragma unroll
  for (int j = 0; j < 4; ++j) {
    const float y0j = y0[o0 + j];
#pragma unroll
    for (int bi = 0; bi < 4; ++bi) acc[bi][j] = y0j;
  }
#pragma unroll 4
  for (int k = 0; k < 384; k += 4) {
    const float4 w0 = vw4[(k + 0) * 2048 + b4];
    const float4 w1 = vw4[(k + 1) * 2048 + b4];
    const float4 w2 = vw4[(k + 2) * 2048 + b4];
    const float4 w3 = vw4[(k + 3) * 2048 + b4];
#pragma unroll
    for (int j = 0; j < 4; ++j) {
      const float4 r = *(const float4*)&Rl[j * 384 + k];
      acc[0][j] += r.x * w0.x + r.y * w1.x + r.z * w2.x + r.w * w3.x;
      acc[1][j] += r.x * w0.y + r.y * w1.y + r.z * w2.y + r.w * w3.y;
      acc[2][j] += r.x * w0.z + r.y * w1.z + r.z * w2.z + r.w * w3.z;
      acc[3][j] += r.x * w0.w + r.y * w1.w + r.z * w2.w + r.w * w3.w;
    }
  }
  const int b0 = b4 * 4;
#pragma unroll
  for (int bi = 0; bi < 4; ++bi) {
    *(float4*)&y[(b0 + bi) * 128 + o0] =
        make_float4(acc[bi][0], acc[bi][1], acc[bi][2], acc[bi][3]);
  }
}

// =================== the one kernel (normal launch, hand-rolled barriers) =========

struct KParams {
  const float *u, *x, *Fm, *B1, *B2, *C1, *C2, *D11, *D12, *D21, *D22, *E, *Lam;
  float* y;
  float *vw, *inv1T, *W, *z1, *STt, *c2p, *inv2T, *g2, *g1, *R, *y0, *cx, *xF,
      *rLam, *cpack;
  unsigned* bar;  // 16 zeroed counters
};

__global__ __launch_bounds__(256) void megak(KParams p) {
  __shared__ __align__(16) float sm[6656];  // union: dev_inv (26.6 KB) is max user
  const int bid = blockIdx.x;
  const int t = threadIdx.x;

  // P1: u-transpose + prep + pack + inv(A11)
  if (bid < 128) dev_T(p.u, p.vw, bid, t, sm);
  else if (bid == 128) dev_prep(p.x, p.C1, p.Fm, p.Lam, p.cx, p.xF, p.rLam, t);
  else if (bid == 129) dev_pack(p.D11, p.cpack, t);
  else if (bid == 130) dev_inv(p.E, 256, p.inv1T, t, sm);
  gbar(p.bar + 0, 256);

  // P2: du (256 units) + WZ (128 units), grid-stride over 384 units
  for (int vb = bid; vb < 384; vb += 256) {
    if (vb < 256) dev_du(p.D12, p.cx, p.vw, vb, t, sm);
    else dev_WZ(p.E, p.C2, p.inv1T, p.W, p.z1, (vb - 256) * 256 + t);
  }
  gbar(p.bar + 1, 256);

  // P3: scan chunk0 + Schur S / c2'
  if (bid < 32) dev_scan(p.cpack, p.rLam, p.vw, 0, bid, t);
  else if (bid < 160) dev_SC(p.E, p.C2, p.W, p.z1, p.STt, p.c2p, (bid - 32) * 256 + t);
  gbar(p.bar + 2, 256);

  // P4: inv(S) + cross-chunk update c=0 (192 tiles)
  if (bid == 0) dev_inv(p.STt, 128, p.inv2T, t, sm);
  else if (bid <= 192) dev_upd(p.D11, p.vw, 0, bid - 1, t);
  gbar(p.bar + 3, 256);

  // P5: scan chunk1 + g2
  if (bid < 32) dev_scan(p.cpack, p.rLam, p.vw, 1, bid, t);
  else if (bid < 96) dev_G2(p.inv2T, p.c2p, p.g2, (bid - 32) * 256 + t);
  gbar(p.bar + 4, 256);

  // P6: update c=1 (128 tiles) + g1
  if (bid < 128) dev_upd(p.D11, p.vw, 1, bid, t);
  else if (bid < 192) dev_G1(p.W, p.z1, p.g2, p.g1, (bid - 128) * 256 + t);
  gbar(p.bar + 5, 256);

  // P7: scan chunk2 + R/y0
  if (bid < 32) dev_scan(p.cpack, p.rLam, p.vw, 2, bid, t);
  else if (bid < 225)
    dev_R(p.B1, p.B2, p.D21, p.D22, p.g1, p.g2, p.xF, p.R, p.y0, (bid - 32) * 256 + t);
  gbar(p.bar + 6, 256);

  // P8: update c=2 (64 tiles)
  if (bid < 64) dev_upd(p.D11, p.vw, 2, bid, t);
  gbar(p.bar + 7, 256);

  // P9: scan chunk3
  if (bid < 32) dev_scan(p.cpack, p.rLam, p.vw, 3, bid, t);
  gbar(p.bar + 8, 256);

  // P10: y = y0 + R * [w; u^T]
  dev_ky(p.vw, p.R, p.y0, p.y, bid, t, sm);
}

extern "C" void kernel_launch(void* const* d_in, const int* in_sizes, int n_in,
                              void* d_out, int out_size, void* d_ws, size_t ws_size,
                              hipStream_t stream) {
  float* F = (float*)d_ws;  // ~13.4 MB used
  float* SMb = F + 384 * NB;

  KParams p;
  p.u = (const float*)d_in[0];
  p.x = (const float*)d_in[1];
  p.Fm = (const float*)d_in[2];
  p.B1 = (const float*)d_in[3];
  p.B2 = (const float*)d_in[4];
  p.C1 = (const float*)d_in[5];
  p.C2 = (const float*)d_in[6];
  p.D11 = (const float*)d_in[7];
  p.D12 = (const float*)d_in[8];
  p.D21 = (const float*)d_in[9];
  p.D22 = (const float*)d_in[10];
  p.E = (const float*)d_in[11];
  p.Lam = (const float*)d_in[12];
  p.y = (float*)d_out;
  p.vw = F;                // 384*8192 (rows 256..383 = u^T)
  p.inv1T = SMb;           // 16384
  p.W = SMb + 16384;
  p.z1 = SMb + 32768;
  p.STt = SMb + 49152;
  p.c2p = SMb + 65536;
  p.inv2T = SMb + 81920;
  p.g2 = SMb + 98304;
  p.g1 = SMb + 114688;
  p.R = SMb + 131072;      // 128*384
  p.y0 = SMb + 180224;     // 128
  p.cx = SMb + 180352;     // 256
  p.xF = SMb + 180608;     // 256
  p.rLam = SMb + 180864;   // 256
  p.cpack = SMb + 181120;  // 4*2176
  p.bar = (unsigned*)(SMb + 181120 + 4 * CPACK_STRIDE);  // 16 counters

  // zero the barrier counters (capture-safe; replayed in-graph before the kernel)
  hipMemsetAsync((void*)p.bar, 0, 16 * sizeof(unsigned), stream);
  megak<<<256, 256, 0, stream>>>(p);
}